// Round 3
// baseline (217.712 us; speedup 1.0000x reference)
//
#include <hip/hip_runtime.h>
#include <math.h>

#define NPIXD 1024
#define GD    2048
#define NCHAND 4
#define NVISD 200000
#define JW    6
#define KXN   1025      // stored kx rows (Hermitian half-plane, kx in [0..1024])
#define RPITCH 1032     // path-A R row pitch in float2 (64B-aligned rows)

static constexpr double PI_D = 3.14159265358979323846;
// tx = uu * (1000 * DL * G), DL = 0.005 * pi/(180*3600)
static constexpr float SCALE_F = (float)(1000.0 * 0.005 * PI_D / (180.0 * 3600.0) * 2048.0);
static constexpr float BETA_F  = (float)(2.34 * 6.0);

// ---------------- apodization table ----------------
__global__ void apod_kernel(float* __restrict__ apod) {
    int i = blockIdx.x * 256 + threadIdx.x;
    if (i >= NPIXD) return;
    float n  = (float)(i - NPIXD / 2) / (float)GD;
    float t  = (float)(PI_D * (double)JW) * n;
    float arg = BETA_F * BETA_F - t * t;
    float sq  = sqrtf(fabsf(arg));
    float ft  = (arg > 0.0f) ? (sinhf(sq) / sq)
                             : ((sq == 0.0f) ? 1.0f : (sinf(sq) / sq));
    apod[i] = 1.0f / ft;
}

// ---------------- 2048-pt Stockham radix-2 FFT in LDS ----------------
__device__ __forceinline__ float2* fft2048(float2* bufA, float2* bufB) {
    float2* src = bufA;
    float2* dst = bufB;
    int mshift = 0;
    for (int stage = 0; stage < 11; ++stage) {
        __syncthreads();
        int m = 1 << mshift;
        #pragma unroll
        for (int jj = 0; jj < 4; ++jj) {
            int j  = (int)threadIdx.x + jj * 256;
            int pm = j & ~(m - 1);                    // floor(j/m)*m
            float ang = (float)pm * (-(float)(PI_D / 1024.0)); // -2*pi*pm/2048
            float sn, cs;
            sincosf(ang, &sn, &cs);
            float2 a = src[j];
            float2 b = src[j + 1024];
            float trx = a.x - b.x, tiy = a.y - b.y;
            dst[j + pm]     = make_float2(a.x + b.x, a.y + b.y);
            dst[j + pm + m] = make_float2(cs * trx - sn * tiy, cs * tiy + sn * trx);
        }
        float2* tmp = src; src = dst; dst = tmp;
        ++mshift;
    }
    __syncthreads();
    return src;
}

// ---- load one image row (roll remap + apodization) into LDS ----
__device__ __forceinline__ void load_row(const float* __restrict__ row,
                                         const float* __restrict__ apod,
                                         float ay, float2* bufA) {
    for (int n = threadIdx.x; n < GD; n += 256) {
        float v = 0.0f;
        if (n < 512)        v = row[n + 512]  * apod[n + 512];
        else if (n >= 1536) v = row[n - 1536] * apod[n - 1536];
        bufA[n] = make_float2(v * ay, 0.0f);
    }
}

// ---------------- pass 1, path A: row FFTs -> coalesced half-width R ----------------
__global__ __launch_bounds__(256) void fft_rows_A(const float* __restrict__ img,
                                                  const float* __restrict__ apod,
                                                  float2* __restrict__ R) {
    __shared__ float2 bufA[GD];
    __shared__ float2 bufB[GD];
    int y = blockIdx.x;
    int c = blockIdx.y;
    load_row(img + ((size_t)c * NPIXD + y) * NPIXD, apod, apod[y], bufA);
    float2* res = fft2048(bufA, bufB);
    float2* outr = R + ((size_t)c * NPIXD + y) * RPITCH;
    for (int kx = threadIdx.x; kx < KXN; kx += 256) outr[kx] = res[kx];
}

// ---------------- transpose (path A): R[c][y][kx] -> Fh[c][kx][y] ----------------
__global__ __launch_bounds__(256) void transpose_A(const float2* __restrict__ R,
                                                   float2* __restrict__ Fh) {
    __shared__ float2 tile[32][33];
    int c   = blockIdx.z;
    int kx0 = blockIdx.x * 32;
    int y0  = blockIdx.y * 32;
    int tx  = threadIdx.x;
    for (int i = threadIdx.y; i < 32; i += 8) {
        if (kx0 + tx < KXN)
            tile[i][tx] = R[((size_t)c * NPIXD + (y0 + i)) * RPITCH + kx0 + tx];
    }
    __syncthreads();
    for (int i = threadIdx.y; i < 32; i += 8) {
        if (kx0 + i < KXN)
            Fh[((size_t)c * KXN + (kx0 + i)) * GD + (y0 + tx)] = tile[tx][i];
    }
}

// ---------------- pass 1, path B: row FFTs -> scattered writes ----------------
__global__ __launch_bounds__(256) void fft_rows_B(const float* __restrict__ img,
                                                  const float* __restrict__ apod,
                                                  float2* __restrict__ Fh) {
    __shared__ float2 bufA[GD];
    __shared__ float2 bufB[GD];
    int y = blockIdx.x;
    int c = blockIdx.y;
    load_row(img + ((size_t)c * NPIXD + y) * NPIXD, apod, apod[y], bufA);
    float2* res = fft2048(bufA, bufB);
    for (int kx = threadIdx.x; kx < KXN; kx += 256)
        Fh[((size_t)c * KXN + kx) * GD + y] = res[kx];
}

// ---------------- pass 2: col FFTs over y, in-place on Fh rows ----------------
__global__ __launch_bounds__(256) void fft_cols_kernel(float2* __restrict__ Fh) {
    __shared__ float2 bufA[GD];
    __shared__ float2 bufB[GD];
    int kx = blockIdx.x;   // 0..1024
    int c  = blockIdx.y;
    float2* rowp = Fh + ((size_t)c * KXN + kx) * GD;
    for (int n = threadIdx.x; n < GD; n += 256) {
        float2 v = make_float2(0.0f, 0.0f);
        if (n < 512)        v = rowp[n + 512];    // y = m+512
        else if (n >= 1536) v = rowp[n - 1536];   // y = m-1536
        bufA[n] = v;
    }
    float2* res = fft2048(bufA, bufB);
    for (int n = threadIdx.x; n < GD; n += 256) rowp[n] = res[n];
}

// ---------------- Kaiser-Bessel weights ----------------
__device__ __forceinline__ float i0f(float x) {
    float ax = fabsf(x);
    if (ax <= 3.75f) {
        float ts = ax / 3.75f; ts *= ts;
        return 1.0f + ts * (3.5156229f + ts * (3.0899424f + ts * (1.2067492f +
                     ts * (0.2659732f + ts * (0.0360768f + ts * 0.0045813f)))));
    } else {
        float t = 3.75f / ax;
        return expf(ax) / sqrtf(ax) *
               (0.39894228f + t * (0.01328592f + t * (0.00225319f + t * (-0.00157565f +
                t * (0.00916281f + t * (-0.02057706f + t * (0.02635537f +
                t * (-0.01647633f + t * 0.00392377f))))))));
    }
}

__device__ __forceinline__ float kbwf(float dist) {
    float r = dist * (2.0f / 6.0f);
    float s = 1.0f - r * r;
    if (s <= 0.0f) return 0.0f;
    return i0f(BETA_F * sqrtf(s)) * (1.0f / 6.0f);
}

// ---------------- gather with Hermitian reconstruction ----------------
// F[c][ky][kx] = Fh[c][kx][ky]                         for kx <= 1024
//             = conj(Fh[c][2048-kx][(2048-ky)&2047])   for kx >  1024
// Output layout decided by out_size (floats):
//   out_size >= 1.6M -> interleaved complex (re,im); else real part only.
__global__ __launch_bounds__(256) void gather_kernel(const float* __restrict__ uu,
                                                     const float* __restrict__ vv,
                                                     const float2* __restrict__ Fh,
                                                     float* __restrict__ out,
                                                     int out_elems, int complexOut) {
    int k = blockIdx.x * 256 + threadIdx.x;
    if (k >= NVISD) return;
    float tx = uu[k] * SCALE_F;
    float ty = vv[k] * SCALE_F;
    float fx = floorf(tx), fy = floorf(ty);
    float wx[JW], wy[JW];
    int   kxe[JW], iy[JW], iyn[JW];
    bool  cj[JW];
    #pragma unroll
    for (int t = 0; t < JW; ++t) {
        float offs = (float)(t - 2);             // -2..3
        wx[t] = kbwf(tx - (fx + offs));
        wy[t] = kbwf(ty - (fy + offs));
        int ix  = ((int)(fx + offs)) & (GD - 1);
        int iyv = ((int)(fy + offs)) & (GD - 1);
        cj[t]  = (ix > 1024);
        kxe[t] = cj[t] ? (GD - ix) : ix;         // in [0..1024]
        iy[t]  = iyv;
        iyn[t] = (GD - iyv) & (GD - 1);
    }
    #pragma unroll
    for (int c = 0; c < NCHAND; ++c) {
        const float2* FhC = Fh + (size_t)c * KXN * GD;
        float sx = 0.0f, sy = 0.0f;
        #pragma unroll
        for (int b = 0; b < JW; ++b) {
            const float2* rp = FhC + (size_t)kxe[b] * GD;
            float wxb = wx[b];
            if (cj[b]) {
                #pragma unroll
                for (int a = 0; a < JW; ++a) {
                    float2 v = rp[iyn[a]];
                    float w  = wxb * wy[a];
                    sx += w * v.x;
                    sy -= w * v.y;   // conjugate
                }
            } else {
                #pragma unroll
                for (int a = 0; a < JW; ++a) {
                    float2 v = rp[iy[a]];
                    float w  = wxb * wy[a];
                    sx += w * v.x;
                    sy += w * v.y;
                }
            }
        }
        size_t idx = (size_t)c * NVISD + k;
        if (complexOut) {
            if (2 * idx + 1 < (size_t)out_elems) {
                out[2 * idx]     = sx;
                out[2 * idx + 1] = sy;
            }
        } else {
            if (idx < (size_t)out_elems) out[idx] = sx;
        }
    }
}

extern "C" void kernel_launch(void* const* d_in, const int* in_sizes, int n_in,
                              void* d_out, int out_size, void* d_ws, size_t ws_size,
                              hipStream_t stream) {
    (void)in_sizes; (void)n_in;
    const float* img = (const float*)d_in[0];
    const float* uu  = (const float*)d_in[1];
    const float* vv  = (const float*)d_in[2];

    const size_t apodBytes = 4096;
    const size_t fhBytes   = (size_t)NCHAND * KXN * GD * sizeof(float2);       // 67,174,400
    const size_t rBytes    = (size_t)NCHAND * NPIXD * RPITCH * sizeof(float2); // 33,816,576
    const size_t needB = apodBytes + fhBytes;            // ~67.2 MB
    const size_t needA = needB + rBytes;                 // ~101.0 MB

    char* ws = (char*)d_ws;
    float*  apod = (float*)ws;
    float2* Fh   = (float2*)(ws + apodBytes);
    float2* R    = (float2*)(ws + apodBytes + fhBytes);

    if (ws_size < needB) return;  // diagnostic: clean numeric failure => ws too small

    int complexOut = (out_size >= 2 * NCHAND * NVISD) ? 1 : 0;

    apod_kernel<<<dim3(4), dim3(256), 0, stream>>>(apod);
    if (ws_size >= needA) {
        fft_rows_A<<<dim3(NPIXD, NCHAND), dim3(256), 0, stream>>>(img, apod, R);
        transpose_A<<<dim3((KXN + 31) / 32, NPIXD / 32, NCHAND), dim3(32, 8), 0, stream>>>(R, Fh);
    } else {
        fft_rows_B<<<dim3(NPIXD, NCHAND), dim3(256), 0, stream>>>(img, apod, Fh);
    }
    fft_cols_kernel<<<dim3(KXN, NCHAND), dim3(256), 0, stream>>>(Fh);
    gather_kernel<<<dim3((NVISD + 255) / 256), dim3(256), 0, stream>>>(
        uu, vv, Fh, (float*)d_out, out_size, complexOut);
}

// Round 4
// 170.880 us; speedup vs baseline: 1.2741x; 1.2741x over previous
//
#include <hip/hip_runtime.h>
#include <math.h>

#define NPIXD 1024
#define GD    2048
#define NCHAND 4
#define NVISD 200000
#define JW    6
#define KXN   1025      // stored kx rows (Hermitian half-plane, kx in [0..1024])
#define RPITCH 1032     // path-A R row pitch in float2 (64B-aligned rows)

static constexpr double PI_D = 3.14159265358979323846;
// tx = uu * (1000 * DL * G), DL = 0.005 * pi/(180*3600)
static constexpr float SCALE_F = (float)(1000.0 * 0.005 * PI_D / (180.0 * 3600.0) * 2048.0);
static constexpr float BETA_F  = (float)(2.34 * 6.0);

// ---------------- apodization table ----------------
__global__ void apod_kernel(float* __restrict__ apod) {
    int i = blockIdx.x * 256 + threadIdx.x;
    if (i >= NPIXD) return;
    float n  = (float)(i - NPIXD / 2) / (float)GD;
    float t  = (float)(PI_D * (double)JW) * n;
    float arg = BETA_F * BETA_F - t * t;
    float sq  = sqrtf(fabsf(arg));
    float ft  = (arg > 0.0f) ? (sinhf(sq) / sq)
                             : ((sq == 0.0f) ? 1.0f : (sinf(sq) / sq));
    apod[i] = 1.0f / ft;
}

// ---------------- twiddle table: tw[t] = exp(-i*pi*t/1024), t in [0,1024) ----------------
__global__ void twiddle_kernel(float2* __restrict__ tw) {
    int t = blockIdx.x * 256 + threadIdx.x;
    if (t >= 1024) return;
    double ang = -PI_D * (double)t / 1024.0;
    tw[t] = make_float2((float)cos(ang), (float)sin(ang));
}

// ---------------- 2048-pt Stockham radix-2 FFT in LDS (table-driven) ----------------
__device__ __forceinline__ float2* fft2048(float2* bufA, float2* bufB,
                                           const float2* __restrict__ twl) {
    float2* src = bufA;
    float2* dst = bufB;
    int mshift = 0;
    for (int stage = 0; stage < 11; ++stage) {
        __syncthreads();
        int m = 1 << mshift;
        #pragma unroll
        for (int jj = 0; jj < 4; ++jj) {
            int j  = (int)threadIdx.x + jj * 256;
            int pm = j & ~(m - 1);                    // floor(j/m)*m, in [0,1024)
            float2 w = twl[pm];
            float2 a = src[j];
            float2 b = src[j + 1024];
            float trx = a.x - b.x, tiy = a.y - b.y;
            dst[j + pm]     = make_float2(a.x + b.x, a.y + b.y);
            dst[j + pm + m] = make_float2(w.x * trx - w.y * tiy, w.x * tiy + w.y * trx);
        }
        float2* tmp = src; src = dst; dst = tmp;
        ++mshift;
    }
    __syncthreads();
    return src;
}

// ---- copy twiddle table global -> LDS (sync happens inside fft2048 stage 0) ----
__device__ __forceinline__ void load_tw(const float2* __restrict__ twg, float2* twl) {
    #pragma unroll
    for (int t = threadIdx.x; t < 1024; t += 256) twl[t] = twg[t];
}

// ---- load one image row (roll remap + apodization) into LDS ----
__device__ __forceinline__ void load_row(const float* __restrict__ row,
                                         const float* __restrict__ apod,
                                         float ay, float2* bufA) {
    for (int n = threadIdx.x; n < GD; n += 256) {
        float v = 0.0f;
        if (n < 512)        v = row[n + 512]  * apod[n + 512];
        else if (n >= 1536) v = row[n - 1536] * apod[n - 1536];
        bufA[n] = make_float2(v * ay, 0.0f);
    }
}

// ---------------- pass 1, path A: row FFTs -> coalesced half-width R ----------------
__global__ __launch_bounds__(256) void fft_rows_A(const float* __restrict__ img,
                                                  const float* __restrict__ apod,
                                                  const float2* __restrict__ twg,
                                                  float2* __restrict__ R) {
    __shared__ float2 bufA[GD];
    __shared__ float2 bufB[GD];
    __shared__ float2 twl[1024];
    int y = blockIdx.x;
    int c = blockIdx.y;
    load_tw(twg, twl);
    load_row(img + ((size_t)c * NPIXD + y) * NPIXD, apod, apod[y], bufA);
    float2* res = fft2048(bufA, bufB, twl);
    float2* outr = R + ((size_t)c * NPIXD + y) * RPITCH;
    for (int kx = threadIdx.x; kx < KXN; kx += 256) outr[kx] = res[kx];
}

// ---------------- transpose (path A): R[c][y][kx] -> Fh[c][kx][y] ----------------
__global__ __launch_bounds__(256) void transpose_A(const float2* __restrict__ R,
                                                   float2* __restrict__ Fh) {
    __shared__ float2 tile[32][33];
    int c   = blockIdx.z;
    int kx0 = blockIdx.x * 32;
    int y0  = blockIdx.y * 32;
    int tx  = threadIdx.x;
    for (int i = threadIdx.y; i < 32; i += 8) {
        if (kx0 + tx < KXN)
            tile[i][tx] = R[((size_t)c * NPIXD + (y0 + i)) * RPITCH + kx0 + tx];
    }
    __syncthreads();
    for (int i = threadIdx.y; i < 32; i += 8) {
        if (kx0 + i < KXN)
            Fh[((size_t)c * KXN + (kx0 + i)) * GD + (y0 + tx)] = tile[tx][i];
    }
}

// ---------------- pass 1, path B: row FFTs -> scattered writes ----------------
__global__ __launch_bounds__(256) void fft_rows_B(const float* __restrict__ img,
                                                  const float* __restrict__ apod,
                                                  const float2* __restrict__ twg,
                                                  float2* __restrict__ Fh) {
    __shared__ float2 bufA[GD];
    __shared__ float2 bufB[GD];
    __shared__ float2 twl[1024];
    int y = blockIdx.x;
    int c = blockIdx.y;
    load_tw(twg, twl);
    load_row(img + ((size_t)c * NPIXD + y) * NPIXD, apod, apod[y], bufA);
    float2* res = fft2048(bufA, bufB, twl);
    for (int kx = threadIdx.x; kx < KXN; kx += 256)
        Fh[((size_t)c * KXN + kx) * GD + y] = res[kx];
}

// ---------------- pass 2: col FFTs over y, in-place on Fh rows ----------------
__global__ __launch_bounds__(256) void fft_cols_kernel(float2* __restrict__ Fh,
                                                       const float2* __restrict__ twg) {
    __shared__ float2 bufA[GD];
    __shared__ float2 bufB[GD];
    __shared__ float2 twl[1024];
    int kx = blockIdx.x;   // 0..1024
    int c  = blockIdx.y;
    load_tw(twg, twl);
    float2* rowp = Fh + ((size_t)c * KXN + kx) * GD;
    for (int n = threadIdx.x; n < GD; n += 256) {
        float2 v = make_float2(0.0f, 0.0f);
        if (n < 512)        v = rowp[n + 512];    // y = m+512
        else if (n >= 1536) v = rowp[n - 1536];   // y = m-1536
        bufA[n] = v;
    }
    float2* res = fft2048(bufA, bufB, twl);
    for (int n = threadIdx.x; n < GD; n += 256) rowp[n] = res[n];
}

// ---------------- Kaiser-Bessel weights ----------------
__device__ __forceinline__ float i0f(float x) {
    float ax = fabsf(x);
    if (ax <= 3.75f) {
        float ts = ax / 3.75f; ts *= ts;
        return 1.0f + ts * (3.5156229f + ts * (3.0899424f + ts * (1.2067492f +
                     ts * (0.2659732f + ts * (0.0360768f + ts * 0.0045813f)))));
    } else {
        float t = 3.75f / ax;
        return expf(ax) / sqrtf(ax) *
               (0.39894228f + t * (0.01328592f + t * (0.00225319f + t * (-0.00157565f +
                t * (0.00916281f + t * (-0.02057706f + t * (0.02635537f +
                t * (-0.01647633f + t * 0.00392377f))))))));
    }
}

__device__ __forceinline__ float kbwf(float dist) {
    float r = dist * (2.0f / 6.0f);
    float s = 1.0f - r * r;
    if (s <= 0.0f) return 0.0f;
    return i0f(BETA_F * sqrtf(s)) * (1.0f / 6.0f);
}

// ---------------- gather with Hermitian reconstruction ----------------
// One thread per (visibility, channel): channel = blockIdx.y. 4x the waves of the
// fused version -> hides scattered L3/L2 read latency.
// F[c][ky][kx] = Fh[c][kx][ky]                         for kx <= 1024
//             = conj(Fh[c][2048-kx][(2048-ky)&2047])   for kx >  1024
__global__ __launch_bounds__(256) void gather_kernel(const float* __restrict__ uu,
                                                     const float* __restrict__ vv,
                                                     const float2* __restrict__ Fh,
                                                     float* __restrict__ out,
                                                     int out_elems, int complexOut) {
    int k = blockIdx.x * 256 + threadIdx.x;
    if (k >= NVISD) return;
    int c = blockIdx.y;
    float tx = uu[k] * SCALE_F;
    float ty = vv[k] * SCALE_F;
    float fx = floorf(tx), fy = floorf(ty);
    float wx[JW], wy[JW];
    int   kxe[JW], iy[JW], iyn[JW];
    bool  cj[JW];
    #pragma unroll
    for (int t = 0; t < JW; ++t) {
        float offs = (float)(t - 2);             // -2..3
        wx[t] = kbwf(tx - (fx + offs));
        wy[t] = kbwf(ty - (fy + offs));
        int ix  = ((int)(fx + offs)) & (GD - 1);
        int iyv = ((int)(fy + offs)) & (GD - 1);
        cj[t]  = (ix > 1024);
        kxe[t] = cj[t] ? (GD - ix) : ix;         // in [0..1024]
        iy[t]  = iyv;
        iyn[t] = (GD - iyv) & (GD - 1);
    }
    const float2* FhC = Fh + (size_t)c * KXN * GD;
    float sx = 0.0f, sy = 0.0f;
    #pragma unroll
    for (int b = 0; b < JW; ++b) {
        const float2* rp = FhC + (size_t)kxe[b] * GD;
        float wxb = wx[b];
        if (cj[b]) {
            #pragma unroll
            for (int a = 0; a < JW; ++a) {
                float2 v = rp[iyn[a]];
                float w  = wxb * wy[a];
                sx += w * v.x;
                sy -= w * v.y;   // conjugate
            }
        } else {
            #pragma unroll
            for (int a = 0; a < JW; ++a) {
                float2 v = rp[iy[a]];
                float w  = wxb * wy[a];
                sx += w * v.x;
                sy += w * v.y;
            }
        }
    }
    size_t idx = (size_t)c * NVISD + k;
    if (complexOut) {
        if (2 * idx + 1 < (size_t)out_elems) {
            out[2 * idx]     = sx;
            out[2 * idx + 1] = sy;
        }
    } else {
        if (idx < (size_t)out_elems) out[idx] = sx;
    }
}

extern "C" void kernel_launch(void* const* d_in, const int* in_sizes, int n_in,
                              void* d_out, int out_size, void* d_ws, size_t ws_size,
                              hipStream_t stream) {
    (void)in_sizes; (void)n_in;
    const float* img = (const float*)d_in[0];
    const float* uu  = (const float*)d_in[1];
    const float* vv  = (const float*)d_in[2];

    const size_t apodBytes = 4096;
    const size_t twBytes   = 1024 * sizeof(float2);                            // 8 KB
    const size_t fhBytes   = (size_t)NCHAND * KXN * GD * sizeof(float2);       // 67,174,400
    const size_t rBytes    = (size_t)NCHAND * NPIXD * RPITCH * sizeof(float2); // 33,816,576
    const size_t needB = apodBytes + twBytes + fhBytes;  // ~67.2 MB
    const size_t needA = needB + rBytes;                 // ~101.0 MB

    char* ws = (char*)d_ws;
    float*  apod = (float*)ws;
    float2* twg  = (float2*)(ws + apodBytes);
    float2* Fh   = (float2*)(ws + apodBytes + twBytes);
    float2* R    = (float2*)(ws + apodBytes + twBytes + fhBytes);

    if (ws_size < needB) return;  // diagnostic: clean numeric failure => ws too small

    int complexOut = (out_size >= 2 * NCHAND * NVISD) ? 1 : 0;

    apod_kernel<<<dim3(4), dim3(256), 0, stream>>>(apod);
    twiddle_kernel<<<dim3(4), dim3(256), 0, stream>>>(twg);
    if (ws_size >= needA) {
        fft_rows_A<<<dim3(NPIXD, NCHAND), dim3(256), 0, stream>>>(img, apod, twg, R);
        transpose_A<<<dim3((KXN + 31) / 32, NPIXD / 32, NCHAND), dim3(32, 8), 0, stream>>>(R, Fh);
    } else {
        fft_rows_B<<<dim3(NPIXD, NCHAND), dim3(256), 0, stream>>>(img, apod, twg, Fh);
    }
    fft_cols_kernel<<<dim3(KXN, NCHAND), dim3(256), 0, stream>>>(Fh, twg);
    gather_kernel<<<dim3((NVISD + 255) / 256, NCHAND), dim3(256), 0, stream>>>(
        uu, vv, Fh, (float*)d_out, out_size, complexOut);
}